// Round 5
// baseline (1265.541 us; speedup 1.0000x reference)
//
#include <hip/hip_runtime.h>

// EncoderBlock on MI355X. Round 5: d_out is fp32 (dataset = bf16-rounded values
// in fp32 storage; round-4 bisection proved math correct, output misaligned).
// MFMA GEMMs (validated vs VALU bit-compare), bf16 activations, fp32 accum.
// B=16 T=1024 C=256 H=8 D=32, BT=16384.

typedef unsigned short u16;
typedef unsigned int u32;
typedef __attribute__((ext_vector_type(8))) short short8v;  // 8 bf16 MFMA A/B frag
typedef __attribute__((ext_vector_type(4))) float float4v;  // MFMA C/D frag

__device__ __forceinline__ float b2f(u16 u) { union { u32 i; float f; } v; v.i = (u32)u << 16; return v.f; }
__device__ __forceinline__ float lo2f(u32 u) { union { u32 i; float f; } v; v.i = u << 16; return v.f; }
__device__ __forceinline__ float hi2f(u32 u) { union { u32 i; float f; } v; v.i = u & 0xffff0000u; return v.f; }
__device__ __forceinline__ u16 f2b(float f) {
    union { float f; u32 i; } v; v.f = f;
    u32 r = v.i + 0x7fffu + ((v.i >> 16) & 1u);  // RTNE (finite values)
    return (u16)(r >> 16);
}
// read element i of an input that is either fp32 (mode=1) or bf16 (mode=0)
__device__ __forceinline__ float rd(const void* p, int i, int mode) {
    return mode ? ((const float*)p)[i] : b2f(((const u16*)p)[i]);
}

// ---------------- dtype detection (proved mode=1 on this dataset; kept) ------
__global__ __launch_bounds__(256) void detect_dtype(const u16* __restrict__ wq_raw,
                                                    int* __restrict__ flag) {
    __shared__ int cnt;
    if (threadIdx.x == 0) cnt = 0;
    __syncthreads();
    int local = 0;
    for (int i = threadIdx.x; i < 4096; i += 256) {
        int e = (wq_raw[i] >> 7) & 0xFF;
        if (e >= 130) local++;
    }
    atomicAdd(&cnt, local);
    __syncthreads();
    if (threadIdx.x == 0) *flag = (cnt > 256) ? 1 : 0;
}

// ---------------- canonicalization ----------------
__global__ __launch_bounds__(256) void canon_x(const void* __restrict__ xin,
                                               u16* __restrict__ xb,
                                               const int* __restrict__ mode) {
    int i = (blockIdx.x * 256 + threadIdx.x) * 4;
    uint2 r;
    if (*mode) {
        float4 v = *(const float4*)((const float*)xin + i);
        r.x = (u32)f2b(v.x) | ((u32)f2b(v.y) << 16);
        r.y = (u32)f2b(v.z) | ((u32)f2b(v.w) << 16);
    } else {
        r = *(const uint2*)((const u16*)xin + i);
    }
    *(uint2*)(xb + i) = r;
}

// biases + ln params -> canonical fp32 cb[2560]:
// [0,256) b_proj | [256,1280) b1 | [1280,1536) b2 | [1536,1792) g1 |
// [1792,2048) be1 | [2048,2304) g2 | [2304,2560) be2
__global__ __launch_bounds__(256) void canon_smalls(const void* bp, const void* b1,
                                                    const void* b2, const void* g1,
                                                    const void* be1, const void* g2,
                                                    const void* be2,
                                                    float* __restrict__ cb,
                                                    const int* __restrict__ mode) {
    int i = blockIdx.x * 256 + threadIdx.x;  // < 2560
    int m = *mode;
    const void* src; int j;
    if (i < 256)       { src = bp;  j = i; }
    else if (i < 1280) { src = b1;  j = i - 256; }
    else if (i < 1536) { src = b2;  j = i - 1280; }
    else if (i < 1792) { src = g1;  j = i - 1536; }
    else if (i < 2048) { src = be1; j = i - 1792; }
    else if (i < 2304) { src = g2;  j = i - 2048; }
    else               { src = be2; j = i - 2304; }
    cb[i] = rd(src, j, m);
}

// wq/wk/wv: (H=8, C=256, D=32) -> wqkvT: (N=768 rows, K=256 cols) bf16, q|k|v
__global__ __launch_bounds__(256) void pack_qkv(const void* __restrict__ wq,
                                                const void* __restrict__ wk,
                                                const void* __restrict__ wv,
                                                u16* __restrict__ outT,
                                                const int* __restrict__ mode) {
    int i = blockIdx.x * 256 + threadIdx.x;           // < 768*256
    int n = i >> 8, k = i & 255;
    int which = n >> 8;                                // 0:q 1:k 2:v
    int nn = n & 255;
    const void* w = which == 0 ? wq : (which == 1 ? wk : wv);
    float v = rd(w, ((nn >> 5) * 256 + k) * 32 + (nn & 31), *mode);  // w[h][k][d]
    outT[i] = f2b(v);
}

// in: (K x N) row-major -> outT: (N x K) bf16 row-major
__global__ __launch_bounds__(256) void transpose_w(const void* __restrict__ in,
                                                   u16* __restrict__ outT, int K, int N,
                                                   const int* __restrict__ mode) {
    int i = blockIdx.x * 256 + threadIdx.x;
    if (i >= K * N) return;
    int n = i / K, k = i - n * K;
    outT[i] = f2b(rd(in, k * N + n, *mode));
}

// ---------------- layernorm (bf16 in, fp32 params, bf16 out) ----------------
__global__ __launch_bounds__(256) void ln_kernel(const u16* __restrict__ xin,
                                                 const float* __restrict__ gw,
                                                 const float* __restrict__ bw,
                                                 u16* __restrict__ out) {
    int row = blockIdx.x * 4 + (threadIdx.x >> 6);
    int lane = threadIdx.x & 63;
    uint2 u = *(const uint2*)(xin + (size_t)row * 256 + lane * 4);
    float v0 = lo2f(u.x), v1 = hi2f(u.x), v2 = lo2f(u.y), v3 = hi2f(u.y);
    float s = v0 + v1 + v2 + v3;
    #pragma unroll
    for (int m = 32; m; m >>= 1) s += __shfl_xor(s, m);
    float mu = s * 0.00390625f;
    float d0 = v0 - mu, d1 = v1 - mu, d2 = v2 - mu, d3 = v3 - mu;
    float ss = d0 * d0 + d1 * d1 + d2 * d2 + d3 * d3;
    #pragma unroll
    for (int m = 32; m; m >>= 1) ss += __shfl_xor(ss, m);
    float rs = rsqrtf(ss * 0.00390625f + 1e-5f);
    float4 g = *(const float4*)(gw + lane * 4);
    float4 b = *(const float4*)(bw + lane * 4);
    uint2 r;
    r.x = (u32)f2b(d0 * rs * g.x + b.x) | ((u32)f2b(d1 * rs * g.y + b.y) << 16);
    r.y = (u32)f2b(d2 * rs * g.z + b.z) | ((u32)f2b(d3 * rs * g.w + b.w) << 16);
    *(uint2*)(out + (size_t)row * 256 + lane * 4) = r;
}

// ---------------- MFMA GEMM (validated by round-4 VALU bisection) ------------
// C[M,N] = A[M,K] @ Bt[N,K]^T (+bias fp32)(+relu)(+resid bf16). 64x64x64 tiles,
// 4 waves 2x2. D: row=(lane>>4)*4+reg, col=lane&15. OUT32: fp32 stores.
template<bool HASBIAS, bool RELU, bool HASRES, bool OUT32>
__global__ __launch_bounds__(256) void gemm_kernel(const u16* __restrict__ A,
                                                   const u16* __restrict__ Bt,
                                                   const float* __restrict__ bias,
                                                   const u16* __restrict__ resid,
                                                   void* __restrict__ out,
                                                   int M, int N, int K) {
    __shared__ __align__(16) u16 As[64][72];   // +8 u16 pad: rows stay 16B-aligned
    __shared__ __align__(16) u16 Bs[64][72];
    int tid = threadIdx.x;
    int m0 = blockIdx.x * 64, n0 = blockIdx.y * 64;
    int lane = tid & 63, wave = tid >> 6;
    int wm = (wave & 1) * 32, wn = (wave >> 1) * 32;
    int fm = lane & 15, q = lane >> 4;
    int lr = tid >> 3, lc = (tid & 7) * 8;     // staging: row 0..31(+32), 8-elem chunk

    float4v acc[2][2];
    #pragma unroll
    for (int i = 0; i < 2; i++)
        #pragma unroll
        for (int j = 0; j < 2; j++) acc[i][j] = (float4v){0.f, 0.f, 0.f, 0.f};

    const uint4* Ag0 = (const uint4*)(A + (size_t)(m0 + lr) * K);
    const uint4* Ag1 = (const uint4*)(A + (size_t)(m0 + lr + 32) * K);
    const uint4* Bg0 = (const uint4*)(Bt + (size_t)(n0 + lr) * K);
    const uint4* Bg1 = (const uint4*)(Bt + (size_t)(n0 + lr + 32) * K);

    for (int k0 = 0; k0 < K; k0 += 64) {
        int kc = (k0 + lc) >> 3;
        uint4 a0 = Ag0[kc], a1 = Ag1[kc], b0 = Bg0[kc], b1 = Bg1[kc];
        __syncthreads();
        *(uint4*)&As[lr][lc] = a0;
        *(uint4*)&As[lr + 32][lc] = a1;
        *(uint4*)&Bs[lr][lc] = b0;
        *(uint4*)&Bs[lr + 32][lc] = b1;
        __syncthreads();
        #pragma unroll
        for (int kk = 0; kk < 64; kk += 32) {
            short8v af0 = *(const short8v*)&As[wm + fm][kk + q * 8];
            short8v af1 = *(const short8v*)&As[wm + 16 + fm][kk + q * 8];
            short8v bf0 = *(const short8v*)&Bs[wn + fm][kk + q * 8];
            short8v bf1 = *(const short8v*)&Bs[wn + 16 + fm][kk + q * 8];
            acc[0][0] = __builtin_amdgcn_mfma_f32_16x16x32_bf16(af0, bf0, acc[0][0], 0, 0, 0);
            acc[0][1] = __builtin_amdgcn_mfma_f32_16x16x32_bf16(af0, bf1, acc[0][1], 0, 0, 0);
            acc[1][0] = __builtin_amdgcn_mfma_f32_16x16x32_bf16(af1, bf0, acc[1][0], 0, 0, 0);
            acc[1][1] = __builtin_amdgcn_mfma_f32_16x16x32_bf16(af1, bf1, acc[1][1], 0, 0, 0);
        }
    }

    #pragma unroll
    for (int mi = 0; mi < 2; mi++)
        #pragma unroll
        for (int ni = 0; ni < 2; ni++) {
            int col = n0 + wn + ni * 16 + fm;
            float bv = HASBIAS ? bias[col] : 0.f;
            #pragma unroll
            for (int r = 0; r < 4; r++) {
                int row = m0 + wm + mi * 16 + q * 4 + r;
                float v = acc[mi][ni][r] + bv;
                if (RELU) v = fmaxf(v, 0.f);
                size_t idx = (size_t)row * N + col;
                if (HASRES) v += b2f(resid[idx]);
                if (OUT32) ((float*)out)[idx] = v;
                else ((u16*)out)[idx] = f2b(v);
            }
        }
}

// ---------------- attention ----------------
// qkv: (B*T, 768) bf16 = [q|k|v] cols, each (b,t,h*32+d). One block per (b,h,t).
__global__ __launch_bounds__(256) void attn_kernel(const u16* __restrict__ qkv,
                                                   u16* __restrict__ att) {
    const int T = 1024;
    int t = blockIdx.x;
    int b = blockIdx.y >> 3, hh = blockIdx.y & 7;
    int tid = threadIdx.x;
    __shared__ float sc[1024];
    __shared__ float qs[32];
    __shared__ float red[8][32];
    __shared__ float wred[4];
    size_t base = (size_t)b * T * 768;
    const u16* qrow = qkv + base + (size_t)t * 768 + hh * 32;
    if (tid < 32) qs[tid] = b2f(qrow[tid]);
    __syncthreads();
    const u16* kbase = qkv + base + 256 + hh * 32;
    float lmax = -1e30f;
    for (int s = tid; s <= t; s += 256) {
        const uint4* kr = (const uint4*)(kbase + (size_t)s * 768);
        float sum = 0.f;
        #pragma unroll
        for (int c = 0; c < 4; c++) {
            uint4 u = kr[c];
            sum += qs[c * 8 + 0] * lo2f(u.x) + qs[c * 8 + 1] * hi2f(u.x)
                 + qs[c * 8 + 2] * lo2f(u.y) + qs[c * 8 + 3] * hi2f(u.y)
                 + qs[c * 8 + 4] * lo2f(u.z) + qs[c * 8 + 5] * hi2f(u.z)
                 + qs[c * 8 + 6] * lo2f(u.w) + qs[c * 8 + 7] * hi2f(u.w);
        }
        sum *= 0.0625f;                     // C^-0.5 = 1/16 (NOT head-size scaling)
        sc[s] = sum;
        lmax = fmaxf(lmax, sum);
    }
    #pragma unroll
    for (int m = 32; m; m >>= 1) lmax = fmaxf(lmax, __shfl_xor(lmax, m));
    if ((tid & 63) == 0) wred[tid >> 6] = lmax;
    __syncthreads();
    float mx = fmaxf(fmaxf(wred[0], wred[1]), fmaxf(wred[2], wred[3]));
    __syncthreads();                        // wred reused below
    float lsum = 0.f;
    for (int s = tid; s <= t; s += 256) {
        float p = __expf(sc[s] - mx);
        sc[s] = p;
        lsum += p;
    }
    #pragma unroll
    for (int m = 32; m; m >>= 1) lsum += __shfl_xor(lsum, m);
    if ((tid & 63) == 0) wred[tid >> 6] = lsum;
    __syncthreads();
    float inv = 1.f / (wred[0] + wred[1] + wred[2] + wred[3]);
    int d = tid & 31, g = tid >> 5;
    const u16* vcol = qkv + base + 512 + hh * 32 + d;
    float a = 0.f;
    for (int s = g; s <= t; s += 8) a += sc[s] * b2f(vcol[(size_t)s * 768]);
    red[g][d] = a;
    __syncthreads();
    if (g == 0) {
        float r = 0.f;
        #pragma unroll
        for (int i = 0; i < 8; i++) r += red[i][d];
        att[(size_t)(b * T + t) * 256 + hh * 32 + d] = f2b(r * inv);
    }
}

// ---------------- launch ----------------
extern "C" void kernel_launch(void* const* d_in, const int* in_sizes, int n_in,
                              void* d_out, int out_size, void* d_ws, size_t ws_size,
                              hipStream_t stream) {
    const int BT = 16 * 1024;  // 16384 rows
    const void* x      = d_in[0];
    const void* wq     = d_in[1];
    const void* wk     = d_in[2];
    const void* wv     = d_in[3];
    const void* w_proj = d_in[4];
    const void* b_proj = d_in[5];
    const void* w1     = d_in[6];
    const void* b1     = d_in[7];
    const void* w2     = d_in[8];
    const void* b2     = d_in[9];
    const void* ln1_g  = d_in[10];
    const void* ln1_b  = d_in[11];
    const void* ln2_g  = d_in[12];
    const void* ln2_b  = d_in[13];

    // Workspace (<50 MiB, identical to rounds 3/4):
    //   [0, 8M)   xb : canonical x (bf16) -> overwritten IN-PLACE by x2 at proj
    //   [8M,16M)  h (LN1 out) -> att -> h2   [serial lifetimes]
    //   [16M,40M) qkv -> [16M,48M) mid (qkv dead after attn)
    //   [48M...)  packed weights (1.5M) + cb + mode flag
    char* ws = (char*)d_ws;
    const size_t MB = 1024 * 1024;
    u16*  xb    = (u16*)(ws + 0);
    u16*  hbuf  = (u16*)(ws + 8 * MB);
    u16*  qkv   = (u16*)(ws + 16 * MB);
    u16*  mid   = (u16*)(ws + 16 * MB);
    u16*  wqkvT = (u16*)(ws + 48 * MB);                 // 384 KiB
    u16*  wpT   = (u16*)(ws + 48 * MB + 0x60000);       // 128 KiB
    u16*  w1T   = (u16*)(ws + 48 * MB + 0x80000);       // 512 KiB
    u16*  w2T   = (u16*)(ws + 48 * MB + 0x100000);      // 512 KiB
    float* cb   = (float*)(ws + 48 * MB + 0x180000);    // 2560 floats
    int*  mode  = (int*)(ws + 48 * MB + 0x184000);

    detect_dtype<<<1, 256, 0, stream>>>((const u16*)wq, mode);
    canon_x<<<BT * 256 / 1024, 256, 0, stream>>>(x, xb, mode);
    canon_smalls<<<10, 256, 0, stream>>>(b_proj, b1, b2, ln1_g, ln1_b, ln2_g, ln2_b, cb, mode);
    pack_qkv<<<768, 256, 0, stream>>>(wq, wk, wv, wqkvT, mode);
    transpose_w<<<256, 256, 0, stream>>>(w_proj, wpT, 256, 256, mode);
    transpose_w<<<1024, 256, 0, stream>>>(w1, w1T, 256, 1024, mode);
    transpose_w<<<1024, 256, 0, stream>>>(w2, w2T, 1024, 256, mode);

    // h = LN1(x)
    ln_kernel<<<BT / 4, 256, 0, stream>>>(xb, cb + 1536, cb + 1792, hbuf);
    // qkv = h @ [Wq|Wk|Wv]
    gemm_kernel<false, false, false, false><<<dim3(BT / 64, 768 / 64), 256, 0, stream>>>(
        hbuf, wqkvT, nullptr, nullptr, qkv, BT, 768, 256);
    // att = causal softmax(q k^T / 16) v  (writes over h, h dead)
    attn_kernel<<<dim3(1024, 128), 256, 0, stream>>>(qkv, hbuf);
    // x2 = x + att @ w_proj + b_proj  (in-place over xb; per-thread same-idx r->w)
    gemm_kernel<true, false, true, false><<<dim3(BT / 64, 256 / 64), 256, 0, stream>>>(
        hbuf, wpT, cb + 0, xb, xb, BT, 256, 256);
    // h2 = LN2(x2)  (writes over att, att dead)
    ln_kernel<<<BT / 4, 256, 0, stream>>>(xb, cb + 2048, cb + 2304, hbuf);
    // mid = relu(h2 @ w1 + b1)  (overlays qkv, qkv dead)
    gemm_kernel<true, true, false, false><<<dim3(BT / 64, 1024 / 64), 256, 0, stream>>>(
        hbuf, w1T, cb + 256, nullptr, mid, BT, 1024, 256);
    // out = x2 + mid @ w2 + b2  -> fp32 stores into d_out
    gemm_kernel<true, false, true, true><<<dim3(BT / 64, 256 / 64), 256, 0, stream>>>(
        mid, w2T, cb + 1280, xb, d_out, BT, 256, 1024);
}

// Round 6
// 322.646 us; speedup vs baseline: 3.9224x; 3.9224x over previous
//
#include <hip/hip_runtime.h>

// EncoderBlock on MI355X. Round 6: MFMA flash-attention replaces scalar attn.
// Inputs fp32 storage (bf16-grid values), d_out fp32. bf16 activations, fp32 accum.
// B=16 T=1024 C=256 H=8 D=32, BT=16384.

typedef unsigned short u16;
typedef unsigned int u32;
typedef __attribute__((ext_vector_type(8))) short short8v;  // 8 bf16 MFMA A/B frag
typedef __attribute__((ext_vector_type(4))) float float4v;  // MFMA C/D frag

__device__ __forceinline__ float b2f(u16 u) { union { u32 i; float f; } v; v.i = (u32)u << 16; return v.f; }
__device__ __forceinline__ float lo2f(u32 u) { union { u32 i; float f; } v; v.i = u << 16; return v.f; }
__device__ __forceinline__ float hi2f(u32 u) { union { u32 i; float f; } v; v.i = u & 0xffff0000u; return v.f; }
__device__ __forceinline__ u16 f2b(float f) {
    union { float f; u32 i; } v; v.f = f;
    u32 r = v.i + 0x7fffu + ((v.i >> 16) & 1u);  // RTNE (finite values)
    return (u16)(r >> 16);
}
__device__ __forceinline__ float rd(const void* p, int i, int mode) {
    return mode ? ((const float*)p)[i] : b2f(((const u16*)p)[i]);
}

// ---------------- dtype detection (proved mode=1 on this dataset; kept) ------
__global__ __launch_bounds__(256) void detect_dtype(const u16* __restrict__ wq_raw,
                                                    int* __restrict__ flag) {
    __shared__ int cnt;
    if (threadIdx.x == 0) cnt = 0;
    __syncthreads();
    int local = 0;
    for (int i = threadIdx.x; i < 4096; i += 256) {
        int e = (wq_raw[i] >> 7) & 0xFF;
        if (e >= 130) local++;
    }
    atomicAdd(&cnt, local);
    __syncthreads();
    if (threadIdx.x == 0) *flag = (cnt > 256) ? 1 : 0;
}

// ---------------- canonicalization ----------------
__global__ __launch_bounds__(256) void canon_x(const void* __restrict__ xin,
                                               u16* __restrict__ xb,
                                               const int* __restrict__ mode) {
    int i = (blockIdx.x * 256 + threadIdx.x) * 4;
    uint2 r;
    if (*mode) {
        float4 v = *(const float4*)((const float*)xin + i);
        r.x = (u32)f2b(v.x) | ((u32)f2b(v.y) << 16);
        r.y = (u32)f2b(v.z) | ((u32)f2b(v.w) << 16);
    } else {
        r = *(const uint2*)((const u16*)xin + i);
    }
    *(uint2*)(xb + i) = r;
}

// biases + ln params -> canonical fp32 cb[2560]:
// [0,256) b_proj | [256,1280) b1 | [1280,1536) b2 | [1536,1792) g1 |
// [1792,2048) be1 | [2048,2304) g2 | [2304,2560) be2
__global__ __launch_bounds__(256) void canon_smalls(const void* bp, const void* b1,
                                                    const void* b2, const void* g1,
                                                    const void* be1, const void* g2,
                                                    const void* be2,
                                                    float* __restrict__ cb,
                                                    const int* __restrict__ mode) {
    int i = blockIdx.x * 256 + threadIdx.x;  // < 2560
    int m = *mode;
    const void* src; int j;
    if (i < 256)       { src = bp;  j = i; }
    else if (i < 1280) { src = b1;  j = i - 256; }
    else if (i < 1536) { src = b2;  j = i - 1280; }
    else if (i < 1792) { src = g1;  j = i - 1536; }
    else if (i < 2048) { src = be1; j = i - 1792; }
    else if (i < 2304) { src = g2;  j = i - 2048; }
    else               { src = be2; j = i - 2304; }
    cb[i] = rd(src, j, m);
}

// wq/wk/wv: (H=8, C=256, D=32) -> wqkvT: (N=768 rows, K=256 cols) bf16, q|k|v
__global__ __launch_bounds__(256) void pack_qkv(const void* __restrict__ wq,
                                                const void* __restrict__ wk,
                                                const void* __restrict__ wv,
                                                u16* __restrict__ outT,
                                                const int* __restrict__ mode) {
    int i = blockIdx.x * 256 + threadIdx.x;           // < 768*256
    int n = i >> 8, k = i & 255;
    int which = n >> 8;                                // 0:q 1:k 2:v
    int nn = n & 255;
    const void* w = which == 0 ? wq : (which == 1 ? wk : wv);
    float v = rd(w, ((nn >> 5) * 256 + k) * 32 + (nn & 31), *mode);  // w[h][k][d]
    outT[i] = f2b(v);
}

// in: (K x N) row-major -> outT: (N x K) bf16 row-major
__global__ __launch_bounds__(256) void transpose_w(const void* __restrict__ in,
                                                   u16* __restrict__ outT, int K, int N,
                                                   const int* __restrict__ mode) {
    int i = blockIdx.x * 256 + threadIdx.x;
    if (i >= K * N) return;
    int n = i / K, k = i - n * K;
    outT[i] = f2b(rd(in, k * N + n, *mode));
}

// ---------------- layernorm (bf16 in, fp32 params, bf16 out) ----------------
__global__ __launch_bounds__(256) void ln_kernel(const u16* __restrict__ xin,
                                                 const float* __restrict__ gw,
                                                 const float* __restrict__ bw,
                                                 u16* __restrict__ out) {
    int row = blockIdx.x * 4 + (threadIdx.x >> 6);
    int lane = threadIdx.x & 63;
    uint2 u = *(const uint2*)(xin + (size_t)row * 256 + lane * 4);
    float v0 = lo2f(u.x), v1 = hi2f(u.x), v2 = lo2f(u.y), v3 = hi2f(u.y);
    float s = v0 + v1 + v2 + v3;
    #pragma unroll
    for (int m = 32; m; m >>= 1) s += __shfl_xor(s, m);
    float mu = s * 0.00390625f;
    float d0 = v0 - mu, d1 = v1 - mu, d2 = v2 - mu, d3 = v3 - mu;
    float ss = d0 * d0 + d1 * d1 + d2 * d2 + d3 * d3;
    #pragma unroll
    for (int m = 32; m; m >>= 1) ss += __shfl_xor(ss, m);
    float rs = rsqrtf(ss * 0.00390625f + 1e-5f);
    float4 g = *(const float4*)(gw + lane * 4);
    float4 b = *(const float4*)(bw + lane * 4);
    uint2 r;
    r.x = (u32)f2b(d0 * rs * g.x + b.x) | ((u32)f2b(d1 * rs * g.y + b.y) << 16);
    r.y = (u32)f2b(d2 * rs * g.z + b.z) | ((u32)f2b(d3 * rs * g.w + b.w) << 16);
    *(uint2*)(out + (size_t)row * 256 + lane * 4) = r;
}

// ---------------- MFMA GEMM (validated) ------------
// C[M,N] = A[M,K] @ Bt[N,K]^T (+bias fp32)(+relu)(+resid bf16). 64x64x64 tiles,
// 4 waves 2x2. D: row=(lane>>4)*4+reg, col=lane&15. OUT32: fp32 stores.
template<bool HASBIAS, bool RELU, bool HASRES, bool OUT32>
__global__ __launch_bounds__(256) void gemm_kernel(const u16* __restrict__ A,
                                                   const u16* __restrict__ Bt,
                                                   const float* __restrict__ bias,
                                                   const u16* __restrict__ resid,
                                                   void* __restrict__ out,
                                                   int M, int N, int K) {
    __shared__ __align__(16) u16 As[64][72];
    __shared__ __align__(16) u16 Bs[64][72];
    int tid = threadIdx.x;
    int m0 = blockIdx.x * 64, n0 = blockIdx.y * 64;
    int lane = tid & 63, wave = tid >> 6;
    int wm = (wave & 1) * 32, wn = (wave >> 1) * 32;
    int fm = lane & 15, q = lane >> 4;
    int lr = tid >> 3, lc = (tid & 7) * 8;

    float4v acc[2][2];
    #pragma unroll
    for (int i = 0; i < 2; i++)
        #pragma unroll
        for (int j = 0; j < 2; j++) acc[i][j] = (float4v){0.f, 0.f, 0.f, 0.f};

    const uint4* Ag0 = (const uint4*)(A + (size_t)(m0 + lr) * K);
    const uint4* Ag1 = (const uint4*)(A + (size_t)(m0 + lr + 32) * K);
    const uint4* Bg0 = (const uint4*)(Bt + (size_t)(n0 + lr) * K);
    const uint4* Bg1 = (const uint4*)(Bt + (size_t)(n0 + lr + 32) * K);

    for (int k0 = 0; k0 < K; k0 += 64) {
        int kc = (k0 + lc) >> 3;
        uint4 a0 = Ag0[kc], a1 = Ag1[kc], b0 = Bg0[kc], b1 = Bg1[kc];
        __syncthreads();
        *(uint4*)&As[lr][lc] = a0;
        *(uint4*)&As[lr + 32][lc] = a1;
        *(uint4*)&Bs[lr][lc] = b0;
        *(uint4*)&Bs[lr + 32][lc] = b1;
        __syncthreads();
        #pragma unroll
        for (int kk = 0; kk < 64; kk += 32) {
            short8v af0 = *(const short8v*)&As[wm + fm][kk + q * 8];
            short8v af1 = *(const short8v*)&As[wm + 16 + fm][kk + q * 8];
            short8v bf0 = *(const short8v*)&Bs[wn + fm][kk + q * 8];
            short8v bf1 = *(const short8v*)&Bs[wn + 16 + fm][kk + q * 8];
            acc[0][0] = __builtin_amdgcn_mfma_f32_16x16x32_bf16(af0, bf0, acc[0][0], 0, 0, 0);
            acc[0][1] = __builtin_amdgcn_mfma_f32_16x16x32_bf16(af0, bf1, acc[0][1], 0, 0, 0);
            acc[1][0] = __builtin_amdgcn_mfma_f32_16x16x32_bf16(af1, bf0, acc[1][0], 0, 0, 0);
            acc[1][1] = __builtin_amdgcn_mfma_f32_16x16x32_bf16(af1, bf1, acc[1][1], 0, 0, 0);
        }
    }

    #pragma unroll
    for (int mi = 0; mi < 2; mi++)
        #pragma unroll
        for (int ni = 0; ni < 2; ni++) {
            int col = n0 + wn + ni * 16 + fm;
            float bv = HASBIAS ? bias[col] : 0.f;
            #pragma unroll
            for (int r = 0; r < 4; r++) {
                int row = m0 + wm + mi * 16 + q * 4 + r;
                float v = acc[mi][ni][r] + bv;
                if (RELU) v = fmaxf(v, 0.f);
                size_t idx = (size_t)row * N + col;
                if (HASRES) v += b2f(resid[idx]);
                if (OUT32) ((float*)out)[idx] = v;
                else ((u16*)out)[idx] = f2b(v);
            }
        }
}

// ---------------- MFMA flash attention ----------------
// qkv: (B*T, 768) bf16 = [q|k|v]. Block = (b,h,64-row Q-tile), 4 waves;
// wave owns 16 Q rows as one 16x16x32 A-frag (k=D=32). Iterate s in 32-steps:
// K staged row-major, V staged transposed; QK^T 2 MFMAs -> online softmax in
// C/D layout -> P via per-wave LDS (C/D -> A-layout; k-perm cancels) -> PV 2
// MFMAs. Causal: block s-range ends at q0+64; diagonal tile masked.
__global__ __launch_bounds__(256) void attn_mfma(const u16* __restrict__ qkv,
                                                 u16* __restrict__ att) {
    const int T = 1024;
    int q0 = blockIdx.x * 64;
    int b = blockIdx.y >> 3, hh = blockIdx.y & 7;
    int tid = threadIdx.x;
    int lane = tid & 63, w = tid >> 6;
    int fm = lane & 15, q = lane >> 4;

    // rows padded to 40 u16 (80 B): all b128 reads 16B-aligned; 2-way banks free
    __shared__ __align__(16) u16 Ks[32][40];
    __shared__ __align__(16) u16 Vt[32][40];
    __shared__ __align__(16) u16 Ps[4][16][40];

    size_t base = (size_t)b * T * 768;
    int tq = q0 + w * 16 + fm;            // Q row for A-frag m=fm
    short8v qf = *(const short8v*)(qkv + base + (size_t)tq * 768 + hh * 32 + q * 8);

    float4v oa = {0.f, 0.f, 0.f, 0.f}, ob = {0.f, 0.f, 0.f, 0.f};
    float mrow[4] = {-1e30f, -1e30f, -1e30f, -1e30f};
    float lrow[4] = {0.f, 0.f, 0.f, 0.f};
    int trow[4];
    #pragma unroll
    for (int r = 0; r < 4; r++) trow[r] = q0 + w * 16 + q * 4 + r;

    int smax = q0 + 64;
    int krow = tid >> 3, kcol = (tid & 7) * 4;      // staging: 32 rows x 32 d
    const u16* kb = qkv + base + 256 + hh * 32;
    const u16* vb = qkv + base + 512 + hh * 32;

    for (int s0 = 0; s0 < smax; s0 += 32) {
        uint2 kv2 = *(const uint2*)(kb + (size_t)(s0 + krow) * 768 + kcol);
        uint2 vv2 = *(const uint2*)(vb + (size_t)(s0 + krow) * 768 + kcol);
        __syncthreads();                  // previous-iter LDS reads done
        *(uint2*)&Ks[krow][kcol] = kv2;
        Vt[kcol + 0][krow] = (u16)(vv2.x & 0xffff);
        Vt[kcol + 1][krow] = (u16)(vv2.x >> 16);
        Vt[kcol + 2][krow] = (u16)(vv2.y & 0xffff);
        Vt[kcol + 3][krow] = (u16)(vv2.y >> 16);
        __syncthreads();

        // S = Q K^T for 32 s-cols
        short8v kf0 = *(const short8v*)&Ks[fm][q * 8];
        short8v kf1 = *(const short8v*)&Ks[16 + fm][q * 8];
        float4v sv0 = {0.f, 0.f, 0.f, 0.f}, sv1 = {0.f, 0.f, 0.f, 0.f};
        sv0 = __builtin_amdgcn_mfma_f32_16x16x32_bf16(qf, kf0, sv0, 0, 0, 0);
        sv1 = __builtin_amdgcn_mfma_f32_16x16x32_bf16(qf, kf1, sv1, 0, 0, 0);

        int sc0 = s0 + fm, sc1 = s0 + 16 + fm;
        float pa[4], pb[4];
        #pragma unroll
        for (int r = 0; r < 4; r++) {
            float a = sv0[r] * 0.0625f;   // C^-0.5 = 1/16
            float c = sv1[r] * 0.0625f;
            if (sc0 > trow[r]) a = -1e30f;
            if (sc1 > trow[r]) c = -1e30f;
            pa[r] = a; pb[r] = c;
        }
        #pragma unroll
        for (int r = 0; r < 4; r++) {
            float tm = fmaxf(pa[r], pb[r]);
            #pragma unroll
            for (int msk = 1; msk < 16; msk <<= 1) tm = fmaxf(tm, __shfl_xor(tm, msk));
            float mnew = fmaxf(mrow[r], tm);
            float alpha = __expf(mrow[r] - mnew);
            mrow[r] = mnew;
            float ea = __expf(pa[r] - mnew);
            float eb = __expf(pb[r] - mnew);
            pa[r] = ea; pb[r] = eb;
            float rs = ea + eb;
            #pragma unroll
            for (int msk = 1; msk < 16; msk <<= 1) rs += __shfl_xor(rs, msk);
            lrow[r] = lrow[r] * alpha + rs;
            oa[r] *= alpha; ob[r] *= alpha;
        }
        // P: C/D layout -> per-wave LDS -> A-frag (wave-internal, DS in-order)
        #pragma unroll
        for (int r = 0; r < 4; r++) {
            Ps[w][q * 4 + r][fm] = f2b(pa[r]);
            Ps[w][q * 4 + r][16 + fm] = f2b(pb[r]);
        }
        short8v pf  = *(const short8v*)&Ps[w][fm][q * 8];
        short8v vf0 = *(const short8v*)&Vt[fm][q * 8];
        short8v vf1 = *(const short8v*)&Vt[16 + fm][q * 8];
        oa = __builtin_amdgcn_mfma_f32_16x16x32_bf16(pf, vf0, oa, 0, 0, 0);
        ob = __builtin_amdgcn_mfma_f32_16x16x32_bf16(pf, vf1, ob, 0, 0, 0);
    }

    #pragma unroll
    for (int r = 0; r < 4; r++) {
        float inv = 1.f / lrow[r];
        size_t o = (size_t)(b * T + trow[r]) * 256 + hh * 32;
        att[o + fm]      = f2b(oa[r] * inv);
        att[o + 16 + fm] = f2b(ob[r] * inv);
    }
}

// ---------------- launch ----------------
extern "C" void kernel_launch(void* const* d_in, const int* in_sizes, int n_in,
                              void* d_out, int out_size, void* d_ws, size_t ws_size,
                              hipStream_t stream) {
    const int BT = 16 * 1024;
    const void* x      = d_in[0];
    const void* wq     = d_in[1];
    const void* wk     = d_in[2];
    const void* wv     = d_in[3];
    const void* w_proj = d_in[4];
    const void* b_proj = d_in[5];
    const void* w1     = d_in[6];
    const void* b1     = d_in[7];
    const void* w2     = d_in[8];
    const void* b2     = d_in[9];
    const void* ln1_g  = d_in[10];
    const void* ln1_b  = d_in[11];
    const void* ln2_g  = d_in[12];
    const void* ln2_b  = d_in[13];

    // Workspace (<50 MiB, identical to round 5):
    char* ws = (char*)d_ws;
    const size_t MB = 1024 * 1024;
    u16*  xb    = (u16*)(ws + 0);
    u16*  hbuf  = (u16*)(ws + 8 * MB);
    u16*  qkv   = (u16*)(ws + 16 * MB);
    u16*  mid   = (u16*)(ws + 16 * MB);
    u16*  wqkvT = (u16*)(ws + 48 * MB);
    u16*  wpT   = (u16*)(ws + 48 * MB + 0x60000);
    u16*  w1T   = (u16*)(ws + 48 * MB + 0x80000);
    u16*  w2T   = (u16*)(ws + 48 * MB + 0x100000);
    float* cb   = (float*)(ws + 48 * MB + 0x180000);
    int*  mode  = (int*)(ws + 48 * MB + 0x184000);

    detect_dtype<<<1, 256, 0, stream>>>((const u16*)wq, mode);
    canon_x<<<BT * 256 / 1024, 256, 0, stream>>>(x, xb, mode);
    canon_smalls<<<10, 256, 0, stream>>>(b_proj, b1, b2, ln1_g, ln1_b, ln2_g, ln2_b, cb, mode);
    pack_qkv<<<768, 256, 0, stream>>>(wq, wk, wv, wqkvT, mode);
    transpose_w<<<256, 256, 0, stream>>>(w_proj, wpT, 256, 256, mode);
    transpose_w<<<1024, 256, 0, stream>>>(w1, w1T, 256, 1024, mode);
    transpose_w<<<1024, 256, 0, stream>>>(w2, w2T, 1024, 256, mode);

    // h = LN1(x)
    ln_kernel<<<BT / 4, 256, 0, stream>>>(xb, cb + 1536, cb + 1792, hbuf);
    // qkv = h @ [Wq|Wk|Wv]
    gemm_kernel<false, false, false, false><<<dim3(BT / 64, 768 / 64), 256, 0, stream>>>(
        hbuf, wqkvT, nullptr, nullptr, qkv, BT, 768, 256);
    // att = flash attention (writes over h, h dead)
    attn_mfma<<<dim3(16, 128), 256, 0, stream>>>(qkv, hbuf);
    // x2 = x + att @ w_proj + b_proj  (in-place over xb)
    gemm_kernel<true, false, true, false><<<dim3(BT / 64, 256 / 64), 256, 0, stream>>>(
        hbuf, wpT, cb + 0, xb, xb, BT, 256, 256);
    // h2 = LN2(x2)
    ln_kernel<<<BT / 4, 256, 0, stream>>>(xb, cb + 2048, cb + 2304, hbuf);
    // mid = relu(h2 @ w1 + b1)
    gemm_kernel<true, true, false, false><<<dim3(BT / 64, 1024 / 64), 256, 0, stream>>>(
        hbuf, w1T, cb + 256, nullptr, mid, BT, 1024, 256);
    // out = x2 + mid @ w2 + b2  -> fp32 stores into d_out
    gemm_kernel<true, false, true, true><<<dim3(BT / 64, 256 / 64), 256, 0, stream>>>(
        mid, w2T, cb + 1280, xb, d_out, BT, 256, 1024);
}

// Round 7
// 234.357 us; speedup vs baseline: 5.4001x; 1.3767x over previous
//
#include <hip/hip_runtime.h>

// EncoderBlock on MI355X. Round 7: attention rebuilt — S^T MFMA layout (queries in
// C/D columns: 2-shuffle softmax, contiguous P stores, O^T accum), paired q-tiles
// for uniform block work. GEMMs/LN unchanged from passing round 6.
// Inputs fp32 storage (bf16-grid values), d_out fp32. B=16 T=1024 C=256 H=8 D=32.

typedef unsigned short u16;
typedef unsigned int u32;
typedef __attribute__((ext_vector_type(8))) short short8v;  // 8 bf16 MFMA A/B frag
typedef __attribute__((ext_vector_type(4))) float float4v;  // MFMA C/D frag

__device__ __forceinline__ float b2f(u16 u) { union { u32 i; float f; } v; v.i = (u32)u << 16; return v.f; }
__device__ __forceinline__ float lo2f(u32 u) { union { u32 i; float f; } v; v.i = u << 16; return v.f; }
__device__ __forceinline__ float hi2f(u32 u) { union { u32 i; float f; } v; v.i = u & 0xffff0000u; return v.f; }
__device__ __forceinline__ u16 f2b(float f) {
    union { float f; u32 i; } v; v.f = f;
    u32 r = v.i + 0x7fffu + ((v.i >> 16) & 1u);  // RTNE (finite values)
    return (u16)(r >> 16);
}
__device__ __forceinline__ float rd(const void* p, int i, int mode) {
    return mode ? ((const float*)p)[i] : b2f(((const u16*)p)[i]);
}

// ---------------- dtype detection (proved mode=1 on this dataset; kept) ------
__global__ __launch_bounds__(256) void detect_dtype(const u16* __restrict__ wq_raw,
                                                    int* __restrict__ flag) {
    __shared__ int cnt;
    if (threadIdx.x == 0) cnt = 0;
    __syncthreads();
    int local = 0;
    for (int i = threadIdx.x; i < 4096; i += 256) {
        int e = (wq_raw[i] >> 7) & 0xFF;
        if (e >= 130) local++;
    }
    atomicAdd(&cnt, local);
    __syncthreads();
    if (threadIdx.x == 0) *flag = (cnt > 256) ? 1 : 0;
}

// ---------------- canonicalization ----------------
__global__ __launch_bounds__(256) void canon_x(const void* __restrict__ xin,
                                               u16* __restrict__ xb,
                                               const int* __restrict__ mode) {
    int i = (blockIdx.x * 256 + threadIdx.x) * 4;
    uint2 r;
    if (*mode) {
        float4 v = *(const float4*)((const float*)xin + i);
        r.x = (u32)f2b(v.x) | ((u32)f2b(v.y) << 16);
        r.y = (u32)f2b(v.z) | ((u32)f2b(v.w) << 16);
    } else {
        r = *(const uint2*)((const u16*)xin + i);
    }
    *(uint2*)(xb + i) = r;
}

// biases + ln params -> canonical fp32 cb[2560]:
// [0,256) b_proj | [256,1280) b1 | [1280,1536) b2 | [1536,1792) g1 |
// [1792,2048) be1 | [2048,2304) g2 | [2304,2560) be2
__global__ __launch_bounds__(256) void canon_smalls(const void* bp, const void* b1,
                                                    const void* b2, const void* g1,
                                                    const void* be1, const void* g2,
                                                    const void* be2,
                                                    float* __restrict__ cb,
                                                    const int* __restrict__ mode) {
    int i = blockIdx.x * 256 + threadIdx.x;  // < 2560
    int m = *mode;
    const void* src; int j;
    if (i < 256)       { src = bp;  j = i; }
    else if (i < 1280) { src = b1;  j = i - 256; }
    else if (i < 1536) { src = b2;  j = i - 1280; }
    else if (i < 1792) { src = g1;  j = i - 1536; }
    else if (i < 2048) { src = be1; j = i - 1792; }
    else if (i < 2304) { src = g2;  j = i - 2048; }
    else               { src = be2; j = i - 2304; }
    cb[i] = rd(src, j, m);
}

// wq/wk/wv: (H=8, C=256, D=32) -> wqkvT: (N=768 rows, K=256 cols) bf16, q|k|v
__global__ __launch_bounds__(256) void pack_qkv(const void* __restrict__ wq,
                                                const void* __restrict__ wk,
                                                const void* __restrict__ wv,
                                                u16* __restrict__ outT,
                                                const int* __restrict__ mode) {
    int i = blockIdx.x * 256 + threadIdx.x;           // < 768*256
    int n = i >> 8, k = i & 255;
    int which = n >> 8;                                // 0:q 1:k 2:v
    int nn = n & 255;
    const void* w = which == 0 ? wq : (which == 1 ? wk : wv);
    float v = rd(w, ((nn >> 5) * 256 + k) * 32 + (nn & 31), *mode);  // w[h][k][d]
    outT[i] = f2b(v);
}

// in: (K x N) row-major -> outT: (N x K) bf16 row-major
__global__ __launch_bounds__(256) void transpose_w(const void* __restrict__ in,
                                                   u16* __restrict__ outT, int K, int N,
                                                   const int* __restrict__ mode) {
    int i = blockIdx.x * 256 + threadIdx.x;
    if (i >= K * N) return;
    int n = i / K, k = i - n * K;
    outT[i] = f2b(rd(in, k * N + n, *mode));
}

// ---------------- layernorm (bf16 in, fp32 params, bf16 out) ----------------
__global__ __launch_bounds__(256) void ln_kernel(const u16* __restrict__ xin,
                                                 const float* __restrict__ gw,
                                                 const float* __restrict__ bw,
                                                 u16* __restrict__ out) {
    int row = blockIdx.x * 4 + (threadIdx.x >> 6);
    int lane = threadIdx.x & 63;
    uint2 u = *(const uint2*)(xin + (size_t)row * 256 + lane * 4);
    float v0 = lo2f(u.x), v1 = hi2f(u.x), v2 = lo2f(u.y), v3 = hi2f(u.y);
    float s = v0 + v1 + v2 + v3;
    #pragma unroll
    for (int m = 32; m; m >>= 1) s += __shfl_xor(s, m);
    float mu = s * 0.00390625f;
    float d0 = v0 - mu, d1 = v1 - mu, d2 = v2 - mu, d3 = v3 - mu;
    float ss = d0 * d0 + d1 * d1 + d2 * d2 + d3 * d3;
    #pragma unroll
    for (int m = 32; m; m >>= 1) ss += __shfl_xor(ss, m);
    float rs = rsqrtf(ss * 0.00390625f + 1e-5f);
    float4 g = *(const float4*)(gw + lane * 4);
    float4 b = *(const float4*)(bw + lane * 4);
    uint2 r;
    r.x = (u32)f2b(d0 * rs * g.x + b.x) | ((u32)f2b(d1 * rs * g.y + b.y) << 16);
    r.y = (u32)f2b(d2 * rs * g.z + b.z) | ((u32)f2b(d3 * rs * g.w + b.w) << 16);
    *(uint2*)(out + (size_t)row * 256 + lane * 4) = r;
}

// ---------------- MFMA GEMM (validated) ------------
template<bool HASBIAS, bool RELU, bool HASRES, bool OUT32>
__global__ __launch_bounds__(256) void gemm_kernel(const u16* __restrict__ A,
                                                   const u16* __restrict__ Bt,
                                                   const float* __restrict__ bias,
                                                   const u16* __restrict__ resid,
                                                   void* __restrict__ out,
                                                   int M, int N, int K) {
    __shared__ __align__(16) u16 As[64][72];
    __shared__ __align__(16) u16 Bs[64][72];
    int tid = threadIdx.x;
    int m0 = blockIdx.x * 64, n0 = blockIdx.y * 64;
    int lane = tid & 63, wave = tid >> 6;
    int wm = (wave & 1) * 32, wn = (wave >> 1) * 32;
    int fm = lane & 15, q = lane >> 4;
    int lr = tid >> 3, lc = (tid & 7) * 8;

    float4v acc[2][2];
    #pragma unroll
    for (int i = 0; i < 2; i++)
        #pragma unroll
        for (int j = 0; j < 2; j++) acc[i][j] = (float4v){0.f, 0.f, 0.f, 0.f};

    const uint4* Ag0 = (const uint4*)(A + (size_t)(m0 + lr) * K);
    const uint4* Ag1 = (const uint4*)(A + (size_t)(m0 + lr + 32) * K);
    const uint4* Bg0 = (const uint4*)(Bt + (size_t)(n0 + lr) * K);
    const uint4* Bg1 = (const uint4*)(Bt + (size_t)(n0 + lr + 32) * K);

    for (int k0 = 0; k0 < K; k0 += 64) {
        int kc = (k0 + lc) >> 3;
        uint4 a0 = Ag0[kc], a1 = Ag1[kc], b0 = Bg0[kc], b1 = Bg1[kc];
        __syncthreads();
        *(uint4*)&As[lr][lc] = a0;
        *(uint4*)&As[lr + 32][lc] = a1;
        *(uint4*)&Bs[lr][lc] = b0;
        *(uint4*)&Bs[lr + 32][lc] = b1;
        __syncthreads();
        #pragma unroll
        for (int kk = 0; kk < 64; kk += 32) {
            short8v af0 = *(const short8v*)&As[wm + fm][kk + q * 8];
            short8v af1 = *(const short8v*)&As[wm + 16 + fm][kk + q * 8];
            short8v bf0 = *(const short8v*)&Bs[wn + fm][kk + q * 8];
            short8v bf1 = *(const short8v*)&Bs[wn + 16 + fm][kk + q * 8];
            acc[0][0] = __builtin_amdgcn_mfma_f32_16x16x32_bf16(af0, bf0, acc[0][0], 0, 0, 0);
            acc[0][1] = __builtin_amdgcn_mfma_f32_16x16x32_bf16(af0, bf1, acc[0][1], 0, 0, 0);
            acc[1][0] = __builtin_amdgcn_mfma_f32_16x16x32_bf16(af1, bf0, acc[1][0], 0, 0, 0);
            acc[1][1] = __builtin_amdgcn_mfma_f32_16x16x32_bf16(af1, bf1, acc[1][1], 0, 0, 0);
        }
    }

    #pragma unroll
    for (int mi = 0; mi < 2; mi++)
        #pragma unroll
        for (int ni = 0; ni < 2; ni++) {
            int col = n0 + wn + ni * 16 + fm;
            float bv = HASBIAS ? bias[col] : 0.f;
            #pragma unroll
            for (int r = 0; r < 4; r++) {
                int row = m0 + wm + mi * 16 + q * 4 + r;
                float v = acc[mi][ni][r] + bv;
                if (RELU) v = fmaxf(v, 0.f);
                size_t idx = (size_t)row * N + col;
                if (HASRES) v += b2f(resid[idx]);
                if (OUT32) ((float*)out)[idx] = v;
                else ((u16*)out)[idx] = f2b(v);
            }
        }
}

// ---------------- MFMA flash attention, S^T layout ----------------
// Block = (b, h, q-tile PAIR {j, 15-j}) -> constant 17 work-units/block.
// Per 64-row q-tile: wave w owns queries [q0+w*16, q0+w*16+16) as C/D COLUMNS.
// S^T = K·Q^T (A=K rows s, B=Q rows m) -> D[s=q*4+r][m=fm]. Softmax per column:
// 8-reg local reduce + shfl_xor(16,32). P^T write = contiguous uint2 into
// Pl[m][s]. O^T += V^T·P (A=Vt rows d, B=Pl rows m) -> D[d=q*4+r][m=fm];
// alpha/1/l scale is per-column fm (no broadcast).
__global__ __launch_bounds__(256) void attn_mfma(const u16* __restrict__ qkv,
                                                 u16* __restrict__ att) {
    const int T = 1024;
    int j = blockIdx.x;                    // 0..7 -> q-tiles j and 15-j
    int b = blockIdx.y >> 3, hh = blockIdx.y & 7;
    int tid = threadIdx.x;
    int lane = tid & 63, w = tid >> 6;
    int fm = lane & 15, q = lane >> 4;

    // rows padded to 40 u16 (80 B): b128 reads 16B-aligned, 2-way banks (free)
    __shared__ __align__(16) u16 Ks[32][40];      // [s][d]
    __shared__ __align__(16) u16 Vt[32][40];      // [d][s]
    __shared__ __align__(16) u16 Pl[4][16][40];   // per-wave P[m][s]

    size_t base = (size_t)b * T * 768;
    const u16* kb = qkv + base + 256 + hh * 32;
    const u16* vb = qkv + base + 512 + hh * 32;
    int krow = tid >> 3, kcol = (tid & 7) * 4;    // K staging: (s, 4 d)
    int vd = tid & 31, vs = (tid >> 5) * 4;       // V staging: (d, 4 s)

    #pragma unroll
    for (int pass = 0; pass < 2; pass++) {
        int q0 = (pass == 0 ? j : 15 - j) * 64;
        int tq = q0 + w * 16 + fm;                // this lane's query (column m=fm)
        short8v qf = *(const short8v*)(qkv + base + (size_t)tq * 768 + hh * 32 + q * 8);

        float4v o0 = {0.f, 0.f, 0.f, 0.f};        // O^T rows d=q*4+r, col m=fm
        float4v o1 = {0.f, 0.f, 0.f, 0.f};        // d+16
        float mst = -1e30f, lst = 0.f;            // per-query state (replicated/quads)
        int wqe = q0 + w * 16 + 16;               // wave's queries end (exclusive)

        for (int s0 = 0; s0 < q0 + 64; s0 += 32) {
            uint2 kv2 = *(const uint2*)(kb + (size_t)(s0 + krow) * 768 + kcol);
            u32 va = (u32)vb[(size_t)(s0 + vs + 0) * 768 + vd]
                   | ((u32)vb[(size_t)(s0 + vs + 1) * 768 + vd] << 16);
            u32 vc = (u32)vb[(size_t)(s0 + vs + 2) * 768 + vd]
                   | ((u32)vb[(size_t)(s0 + vs + 3) * 768 + vd] << 16);
            __syncthreads();                      // prior LDS reads complete
            *(uint2*)&Ks[krow][kcol] = kv2;
            *(uint2*)&Vt[vd][vs] = (uint2){va, vc};
            __syncthreads();

            if (s0 < wqe) {                       // wave-uniform causal skip
                short8v kf0 = *(const short8v*)&Ks[fm][q * 8];
                short8v kf1 = *(const short8v*)&Ks[16 + fm][q * 8];
                float4v sv0 = {0.f, 0.f, 0.f, 0.f}, sv1 = {0.f, 0.f, 0.f, 0.f};
                sv0 = __builtin_amdgcn_mfma_f32_16x16x32_bf16(kf0, qf, sv0, 0, 0, 0);
                sv1 = __builtin_amdgcn_mfma_f32_16x16x32_bf16(kf1, qf, sv1, 0, 0, 0);

                float e[8];
                int sb = s0 + q * 4;
                #pragma unroll
                for (int r = 0; r < 4; r++) {
                    float a = sv0[r] * 0.0625f;   // C^-0.5 = 1/16
                    float c = sv1[r] * 0.0625f;
                    if (sb + r > tq) a = -1e30f;
                    if (sb + 16 + r > tq) c = -1e30f;
                    e[r] = a; e[4 + r] = c;
                }
                float tm = fmaxf(fmaxf(fmaxf(e[0], e[1]), fmaxf(e[2], e[3])),
                                 fmaxf(fmaxf(e[4], e[5]), fmaxf(e[6], e[7])));
                tm = fmaxf(tm, __shfl_xor(tm, 16));
                tm = fmaxf(tm, __shfl_xor(tm, 32));
                float mnew = fmaxf(mst, tm);
                float alpha = __expf(mst - mnew);
                mst = mnew;
                float rs = 0.f;
                #pragma unroll
                for (int i = 0; i < 8; i++) { e[i] = __expf(e[i] - mnew); rs += e[i]; }
                rs += __shfl_xor(rs, 16);
                rs += __shfl_xor(rs, 32);
                lst = lst * alpha + rs;
                #pragma unroll
                for (int r = 0; r < 4; r++) { o0[r] *= alpha; o1[r] *= alpha; }

                // P^T -> Pl[m][s]: lane holds P[m=fm][s0+q*4+r], contiguous
                uint2 p0, p1;
                p0.x = (u32)f2b(e[0]) | ((u32)f2b(e[1]) << 16);
                p0.y = (u32)f2b(e[2]) | ((u32)f2b(e[3]) << 16);
                p1.x = (u32)f2b(e[4]) | ((u32)f2b(e[5]) << 16);
                p1.y = (u32)f2b(e[6]) | ((u32)f2b(e[7]) << 16);
                *(uint2*)&Pl[w][fm][q * 4] = p0;       // wave-internal: DS in-order,
                *(uint2*)&Pl[w][fm][16 + q * 4] = p1;  // no barrier needed

                short8v pf  = *(const short8v*)&Pl[w][fm][q * 8];
                short8v vf0 = *(const short8v*)&Vt[fm][q * 8];
                short8v vf1 = *(const short8v*)&Vt[16 + fm][q * 8];
                o0 = __builtin_amdgcn_mfma_f32_16x16x32_bf16(vf0, pf, o0, 0, 0, 0);
                o1 = __builtin_amdgcn_mfma_f32_16x16x32_bf16(vf1, pf, o1, 0, 0, 0);
            }
        }

        float inv = 1.f / lst;
        uint2 r0, r1;
        r0.x = (u32)f2b(o0[0] * inv) | ((u32)f2b(o0[1] * inv) << 16);
        r0.y = (u32)f2b(o0[2] * inv) | ((u32)f2b(o0[3] * inv) << 16);
        r1.x = (u32)f2b(o1[0] * inv) | ((u32)f2b(o1[1] * inv) << 16);
        r1.y = (u32)f2b(o1[2] * inv) | ((u32)f2b(o1[3] * inv) << 16);
        size_t o = (size_t)(b * T + tq) * 256 + hh * 32;
        *(uint2*)(att + o + q * 4) = r0;        // d = q*4..q*4+3
        *(uint2*)(att + o + 16 + q * 4) = r1;   // d+16
        __syncthreads();                        // protect Ks/Vt before next pass
    }
}

// ---------------- launch ----------------
extern "C" void kernel_launch(void* const* d_in, const int* in_sizes, int n_in,
                              void* d_out, int out_size, void* d_ws, size_t ws_size,
                              hipStream_t stream) {
    const int BT = 16 * 1024;
    const void* x      = d_in[0];
    const void* wq     = d_in[1];
    const void* wk     = d_in[2];
    const void* wv     = d_in[3];
    const void* w_proj = d_in[4];
    const void* b_proj = d_in[5];
    const void* w1     = d_in[6];
    const void* b1     = d_in[7];
    const void* w2     = d_in[8];
    const void* b2     = d_in[9];
    const void* ln1_g  = d_in[10];
    const void* ln1_b  = d_in[11];
    const void* ln2_g  = d_in[12];
    const void* ln2_b  = d_in[13];

    // Workspace (<50 MiB, identical to rounds 5/6):
    char* ws = (char*)d_ws;
    const size_t MB = 1024 * 1024;
    u16*  xb    = (u16*)(ws + 0);
    u16*  hbuf  = (u16*)(ws + 8 * MB);
    u16*  qkv   = (u16*)(ws + 16 * MB);
    u16*  mid   = (u16*)(ws + 16 * MB);
    u16*  wqkvT = (u16*)(ws + 48 * MB);
    u16*  wpT   = (u16*)(ws + 48 * MB + 0x60000);
    u16*  w1T   = (u16*)(ws + 48 * MB + 0x80000);
    u16*  w2T   = (u16*)(ws + 48 * MB + 0x100000);
    float* cb   = (float*)(ws + 48 * MB + 0x180000);
    int*  mode  = (int*)(ws + 48 * MB + 0x184000);

    detect_dtype<<<1, 256, 0, stream>>>((const u16*)wq, mode);
    canon_x<<<BT * 256 / 1024, 256, 0, stream>>>(x, xb, mode);
    canon_smalls<<<10, 256, 0, stream>>>(b_proj, b1, b2, ln1_g, ln1_b, ln2_g, ln2_b, cb, mode);
    pack_qkv<<<768, 256, 0, stream>>>(wq, wk, wv, wqkvT, mode);
    transpose_w<<<256, 256, 0, stream>>>(w_proj, wpT, 256, 256, mode);
    transpose_w<<<1024, 256, 0, stream>>>(w1, w1T, 256, 1024, mode);
    transpose_w<<<1024, 256, 0, stream>>>(w2, w2T, 1024, 256, mode);

    // h = LN1(x)
    ln_kernel<<<BT / 4, 256, 0, stream>>>(xb, cb + 1536, cb + 1792, hbuf);
    // qkv = h @ [Wq|Wk|Wv]
    gemm_kernel<false, false, false, false><<<dim3(BT / 64, 768 / 64), 256, 0, stream>>>(
        hbuf, wqkvT, nullptr, nullptr, qkv, BT, 768, 256);
    // att = flash attention (writes over h, h dead); paired q-tiles, grid (8,128)
    attn_mfma<<<dim3(8, 128), 256, 0, stream>>>(qkv, hbuf);
    // x2 = x + att @ w_proj + b_proj  (in-place over xb)
    gemm_kernel<true, false, true, false><<<dim3(BT / 64, 256 / 64), 256, 0, stream>>>(
        hbuf, wpT, cb + 0, xb, xb, BT, 256, 256);
    // h2 = LN2(x2)
    ln_kernel<<<BT / 4, 256, 0, stream>>>(xb, cb + 2048, cb + 2304, hbuf);
    // mid = relu(h2 @ w1 + b1)
    gemm_kernel<true, true, false, false><<<dim3(BT / 64, 1024 / 64), 256, 0, stream>>>(
        hbuf, w1T, cb + 256, nullptr, mid, BT, 1024, 256);
    // out = x2 + mid @ w2 + b2  -> fp32 stores into d_out
    gemm_kernel<true, false, true, true><<<dim3(BT / 64, 256 / 64), 256, 0, stream>>>(
        mid, w2T, cb + 1280, xb, d_out, BT, 256, 1024);
}